// Round 1
// baseline (1009.696 us; speedup 1.0000x reference)
//
#include <hip/hip_runtime.h>

#define NBATCH 64
#define NCH    128
#define NTYPE  6
#define NK     127
#define N1     25
#define N2     50
#define N3     100
#define NAXIS  4
#define OUTPER 400  // N3*NAXIS
#define W2P    28   // W2 row padded to 28 floats -> every row 16B-aligned (float4 reads)
#define MAXKP  152  // padded sorted-k capacity (127 + 6*3 = 145)
#define MAXC4  38   // max 4-k chunks
#define NQ     13   // i-granules of 4 in phase 2 (50 real + 2 zero-pad = 52)

// ---------- repetition macros: straight-line code, literal indices ONLY ----------
#define R5(M)  M(0) M(1) M(2) M(3) M(4)
#define R7(M)  M(0) M(1) M(2) M(3) M(4) M(5) M(6)
#define R12(M) M(0) M(1) M(2) M(3) M(4) M(5) M(6) M(7) M(8) M(9) M(10) M(11)
#define R25(M) M(0) M(1) M(2) M(3) M(4) M(5) M(6) M(7) M(8) M(9) M(10) M(11) M(12) \
               M(13) M(14) M(15) M(16) M(17) M(18) M(19) M(20) M(21) M(22) M(23) M(24)
#define R25A(M,a) M(a,0) M(a,1) M(a,2) M(a,3) M(a,4) M(a,5) M(a,6) M(a,7) M(a,8) M(a,9) \
               M(a,10) M(a,11) M(a,12) M(a,13) M(a,14) M(a,15) M(a,16) M(a,17) M(a,18) \
               M(a,19) M(a,20) M(a,21) M(a,22) M(a,23) M(a,24)
#define R50(M) R25(M) M(25) M(26) M(27) M(28) M(29) M(30) M(31) M(32) M(33) M(34) \
               M(35) M(36) M(37) M(38) M(39) M(40) M(41) M(42) M(43) M(44) M(45) \
               M(46) M(47) M(48) M(49)

__device__ __forceinline__ float tanh_fast(float x) {
    float e = __expf(2.0f * x);                       // e^{2x}; inf/0 saturate correctly
    return 1.0f - 2.0f * __builtin_amdgcn_rcpf(e + 1.0f);
}

// coords (NB,NC,3) -> ct[(j*3+d)*NB + b]  (lane=b contiguous)
__global__ void k_transpose(const float* __restrict__ coords, float* __restrict__ ct) {
    int t = blockIdx.x * blockDim.x + threadIdx.x;
    if (t >= NBATCH * NCH * 3) return;
    int b  = t & (NBATCH - 1);
    int jd = t >> 6;
    int d  = jd % 3;
    int j  = jd / 3;
    ct[t] = coords[(b * NCH + j) * 3 + d];
}

// plain counting sort (k_mlp)
__device__ __forceinline__ void sort_k_by_type(
    const int* __restrict__ types, int n, int* tysh, int* ks, int* bins, int tid, int nthr)
{
    for (int t = tid; t < NCH; t += nthr) tysh[t] = types[t];
    __syncthreads();
    if (tid == 0) {
        for (int t = 0; t < NTYPE; ++t) bins[t] = 0;
        for (int k = 0; k < NK; ++k) { int j = (k < n) ? k : k + 1; bins[tysh[j]]++; }
        int off = 0;
        for (int t = 0; t < NTYPE; ++t) { int c = bins[t]; bins[t] = off; off += c; }
        for (int k = 0; k < NK; ++k) { int j = (k < n) ? k : k + 1; ks[bins[tysh[j]]++] = k; }
    }
    __syncthreads();
}

// padded counting sort: each 4-k chunk has ONE neighbor type; pads = -1.
// chs[chunk] = neighbor type, aux[0] = number of chunks.
__device__ __forceinline__ void sort_pad(
    const int* __restrict__ types, int n, int* tysh, int* ksp, int* chs, int* aux,
    int tid, int nthr)
{
    for (int t = tid; t < NCH; t += nthr) tysh[t] = types[t];
    __syncthreads();
    if (tid == 0) {
        int cnt[NTYPE], pos[NTYPE];
        for (int t = 0; t < NTYPE; ++t) cnt[t] = 0;
        for (int k = 0; k < NK; ++k) { int j = (k < n) ? k : k + 1; cnt[tysh[j]]++; }
        int c = 0;
        for (int t = 0; t < NTYPE; ++t) {
            pos[t] = c;
            int pc = (cnt[t] + 3) & ~3;
            for (int q = c >> 2; q < (c + pc) >> 2; ++q) chs[q] = t;
            for (int p = c + cnt[t]; p < c + pc; ++p) ksp[p] = -1;
            c += pc;
        }
        aux[0] = c >> 2;
        for (int k = 0; k < NK; ++k) { int j = (k < n) ? k : k + 1; ksp[pos[tysh[j]]++] = k; }
    }
    __syncthreads();
}

// Kernel A: unchanged round-10 structure (sorted k, wave-uniform s_load weights).
__global__ __launch_bounds__(256, 4) void k_mlp(
    const float* __restrict__ ct, const int* __restrict__ types,
    const float* __restrict__ W1, const float* __restrict__ B1,
    const float* __restrict__ W2, const float* __restrict__ B2,
    const float* __restrict__ W3, const float* __restrict__ B3,
    float* __restrict__ t1buf)
{
    __shared__ int ks[NK];
    __shared__ int tysh[NCH];
    __shared__ int bins[NTYPE];

    const int n  = blockIdx.x >> 2;
    const int qc = blockIdx.x & 3;
    const int w  = threadIdx.x >> 6;
    const int b  = threadIdx.x & 63;
    const int k0 = qc * 32 + w * 8;

    sort_k_by_type(types, n, tysh, ks, bins, threadIdx.x, 256);

    const float cx = ct[(n*3+0)*NBATCH + b];
    const float cy = ct[(n*3+1)*NBATCH + b];
    const float cz = ct[(n*3+2)*NBATCH + b];
    const int tn = __builtin_amdgcn_readfirstlane(tysh[n]);

    float t1a[12];
#define TIN(i) t1a[i] = 0.0f;
    R12(TIN)
#undef TIN

    for (int kk = 0; kk < 8; ++kk) {
        const int kidx = k0 + kk;
        if (kidx >= NK) break;
        const int sk = __builtin_amdgcn_readfirstlane(ks[kidx]);
        const int j  = (sk < n) ? sk : sk + 1;
        const int ch = __builtin_amdgcn_readfirstlane(tn * NTYPE + tysh[j]);

        const float dx = cx - ct[(j*3+0)*NBATCH + b];
        const float dy = cy - ct[(j*3+1)*NBATCH + b];
        const float dz = cz - ct[(j*3+2)*NBATCH + b];
        const float d2 = dx*dx + dy*dy + dz*dz;
        const float dd = sqrtf(d2);
        const float dinv = __builtin_amdgcn_rcpf(fmaxf(dd, 1e-12f));
        const float di2 = dinv * dinv;
        const float ax = dx * di2, ay = dy * di2, az = dz * di2;

        const float* w1r = W1 + ch * N1;
        const float* b1r = B1 + ch * N1;
        float y1[N1];
#define L1S(o) y1[o] = tanh_fast(fmaf(dinv, w1r[o], b1r[o]));
        R25(L1S)
#undef L1S

        const float* w2r = W2 + ch * (N2 * N1);
        const float* b2r = B2 + ch * N2;
        const float* w3r = W3 + ch * (N3 * N2);
        float zf[4];
        zf[0] = B3[ch*N3+0]; zf[1] = B3[ch*N3+1];
        zf[2] = B3[ch*N3+2]; zf[3] = B3[ch*N3+3];
        float r[4];
#define MLP2I(o,i) z = fmaf(w2r[(o)*N1+(i)], y1[i], z);
#define MLP2(o) { float z = b2r[o]; R25A(MLP2I,o) \
        float y2o = tanh_fast(z) + y1[(o)%N1]; \
        if ((o) < 4) r[(o)&3] = y2o; \
        zf[0] = fmaf(w3r[0*N2+(o)], y2o, zf[0]); \
        zf[1] = fmaf(w3r[1*N2+(o)], y2o, zf[1]); \
        zf[2] = fmaf(w3r[2*N2+(o)], y2o, zf[2]); \
        zf[3] = fmaf(w3r[3*N2+(o)], y2o, zf[3]); }
        R50(MLP2)
#undef MLP2
#undef MLP2I

#define O4F(f) { float o4 = tanh_fast(zf[f]) + r[f]; \
        t1a[0+(f)] = fmaf(ax, o4, t1a[0+(f)]); \
        t1a[4+(f)] = fmaf(ay, o4, t1a[4+(f)]); \
        t1a[8+(f)] = fmaf(az, o4, t1a[8+(f)]); }
        O4F(0) O4F(1) O4F(2) O4F(3)
#undef O4F
    }

    float* dst = t1buf + (n * 12) * NBATCH + b;   // [n][i][b] lane-coalesced
#define TAT(i) atomicAdd(dst + (i) * NBATCH, t1a[i]);
    R12(TAT)
#undef TAT
}

// Kernel B v2: (1) y2 staged in LDS as [k][i-granule][b][4] so phase-2 reads
// are conflict-free ds_read_b128 (16B lane stride; 200 b32 -> ~56 b128 per
// wave-chunk); (2) layer-3 i-granule fused across all 4 k's of the chunk:
// one 28-dword uniform W3 load feeds 112 FMAs (W3 scalar volume halved vs
// per-k-pair reload); (3) padded k's staged as ZEROS (y2 + t2) so phase 2 is
// guard-free straight-line; (4) launch_bounds (512,4): VGPR cap 128 -- free,
// LDS 64.6KB already caps residency at 2 blocks/CU (= 4 waves/SIMD).
__global__ __launch_bounds__(512, 4) void k_res2(
    const float* __restrict__ ct, const int* __restrict__ types,
    const float* __restrict__ W1, const float* __restrict__ B1,
    const float* __restrict__ W2, const float* __restrict__ B2,
    const float* __restrict__ W3, const float* __restrict__ B3,
    const float* __restrict__ t1buf, float* __restrict__ out)
{
    __shared__ float y2t[4 * NQ * NBATCH * 4];     // 53248 B  [k][q][b][4]
    __shared__ float t2s[4 * NBATCH * NAXIS];      //  4096 B
    __shared__ float w2s[N2 * W2P];                //  5600 B (rows padded to 28)
    __shared__ float w1s[N1], b1s[N1], b2s[N2];
    __shared__ int   ksp[MAXKP];
    __shared__ int   chs[MAXC4];
    __shared__ int   tysh[NCH];
    __shared__ int   aux[1];

#define Y2I(k,q,b,j) ((((k)*NQ + (q))*NBATCH + (b))*4 + (j))

    const int n    = blockIdx.x >> 2;
    const int gh   = (blockIdx.x >> 1) & 1;
    const int kh   = blockIdx.x & 1;
    const int w    = threadIdx.x >> 6;
    const int lane = threadIdx.x & 63;            // = b in both phases
    const int kk2  = w >> 1;                      // phase-1 k of chunk
    const int h    = w & 1;                       // phase-1 y2 half
    const int tid  = threadIdx.x;

    sort_pad(types, n, tysh, ksp, chs, aux, tid, 512);
    const int nch4 = __builtin_amdgcn_readfirstlane(aux[0]);
    const int c_lo = kh ? (nch4 >> 1) : 0;
    const int c_hi = kh ? nch4 : (nch4 >> 1);

    const int tn = __builtin_amdgcn_readfirstlane(tysh[n]);

    const float cx = ct[(n*3+0)*NBATCH + lane];
    const float cy = ct[(n*3+1)*NBATCH + lane];
    const float cz = ct[(n*3+2)*NBATCH + lane];

    float t1r[12];
#define T1L(i) t1r[i] = t1buf[(n*12 + (i))*NBATCH + lane];
    R12(T1L)
#undef T1L

    const int g0 = __builtin_amdgcn_readfirstlane(w * 7);
    int gg[7];
#define GGI(gi) gg[gi] = ((g0 + (gi)) < N2) ? (g0 + (gi)) : (N2 - 1);
    R7(GGI)
#undef GGI

    float racc[7][4];
#define RIN(gi) racc[gi][0]=0.f; racc[gi][1]=0.f; racc[gi][2]=0.f; racc[gi][3]=0.f;
    R7(RIN)
#undef RIN

    float b3v[7];
    int prevty = -1;

    for (int kc = c_lo; kc < c_hi; ++kc) {
        const int tj = __builtin_amdgcn_readfirstlane(chs[kc]);
        const int ch = tn * NTYPE + tj;
        if (tj != prevty) {                        // block-uniform branch
            // stage channel weights to LDS (prev P2 done: trailing barrier)
            for (int idx = tid; idx < N2*N1; idx += 512)
                w2s[(idx / N1) * W2P + (idx % N1)] = W2[ch*(N2*N1) + idx];
            if (tid < N1) { w1s[tid] = W1[ch*N1+tid]; b1s[tid] = B1[ch*N1+tid]; }
            if (tid < N2) b2s[tid] = B2[ch*N2+tid];
#define B3L(gi) b3v[gi] = B3[ch*N3 + gh*N2 + gg[gi]];
            R7(B3L)
#undef B3L
            prevty = tj;
            __syncthreads();
        }
        const int kb = kc * 4;
        // ================= phase 1: stage y2 (+t2) for 4 k's (one channel) ========
        {
            const int sk = __builtin_amdgcn_readfirstlane(ksp[kb + kk2]);
            if (sk >= 0) {
                const int j = (sk < n) ? sk : sk + 1;
                const float dx = cx - ct[(j*3+0)*NBATCH + lane];
                const float dy = cy - ct[(j*3+1)*NBATCH + lane];
                const float dz = cz - ct[(j*3+2)*NBATCH + lane];
                const float d2 = dx*dx + dy*dy + dz*dz;
                const float dd = sqrtf(d2);
                const float dinv = __builtin_amdgcn_rcpf(fmaxf(dd, 1e-12f));

                if (h == 0) {
                    const float di2 = dinv * dinv;
                    const float ax = dx * di2, ay = dy * di2, az = dz * di2;
                    float4 t2v;
                    t2v.x = ax*t1r[0] + ay*t1r[4] + az*t1r[8];
                    t2v.y = ax*t1r[1] + ay*t1r[5] + az*t1r[9];
                    t2v.z = ax*t1r[2] + ay*t1r[6] + az*t1r[10];
                    t2v.w = ax*t1r[3] + ay*t1r[7] + az*t1r[11];
                    *(float4*)&t2s[(kk2*NBATCH + lane)*NAXIS] = t2v;
                }

                float y1[N1];
#define L1S(o) y1[o] = tanh_fast(fmaf(dinv, w1s[o], b1s[o]));
                R25(L1S)
#undef L1S
                const int ob = h * N1;            // 0 or 25
                // yo[oi] = y2[ob+oi]; residual y1[(ob+oi)%25] = y1[oi] for both h.
                float yo[N1];
#define P1Q(oi,q) { float4 wq = *(const float4*)&w2s[(ob+(oi))*W2P + (q)*4]; \
                    z = fmaf(wq.x, y1[(q)*4+0], z); z = fmaf(wq.y, y1[(q)*4+1], z); \
                    z = fmaf(wq.z, y1[(q)*4+2], z); z = fmaf(wq.w, y1[(q)*4+3], z); }
#define P1S(oi) { float z = b2s[ob+(oi)]; \
                  P1Q(oi,0) P1Q(oi,1) P1Q(oi,2) P1Q(oi,3) P1Q(oi,4) P1Q(oi,5) \
                  z = fmaf(w2s[(ob+(oi))*W2P + 24], y1[24], z); \
                  yo[oi] = tanh_fast(z) + y1[oi]; }
#define ST4(q,a0,a1,a2,a3) { float4 v; v.x=(a0); v.y=(a1); v.z=(a2); v.w=(a3); \
                  *(float4*)&y2t[Y2I(kk2,(q),lane,0)] = v; }
                // interleave compute/store per 4 outputs to keep yo lifetimes short.
                // h=0 covers o 0..24 (granules 0..5 + g6 slot0);
                // h=1 covers o 25..49 (g6 slots 1..3, granules 7..11, g12={48,49,0,0}).
                P1S(0) P1S(1) P1S(2) P1S(3)
                if (h == 0) { ST4(0, yo[0],yo[1],yo[2],yo[3]) }
                else { y2t[Y2I(kk2,6,lane,1)] = yo[0];
                       y2t[Y2I(kk2,6,lane,2)] = yo[1];
                       y2t[Y2I(kk2,6,lane,3)] = yo[2]; }
                P1S(4) P1S(5) P1S(6) P1S(7)
                if (h == 0) { ST4(1, yo[4],yo[5],yo[6],yo[7]) }
                else        { ST4(7, yo[3],yo[4],yo[5],yo[6]) }
                P1S(8) P1S(9) P1S(10) P1S(11)
                if (h == 0) { ST4(2, yo[8],yo[9],yo[10],yo[11]) }
                else        { ST4(8, yo[7],yo[8],yo[9],yo[10]) }
                P1S(12) P1S(13) P1S(14) P1S(15)
                if (h == 0) { ST4(3, yo[12],yo[13],yo[14],yo[15]) }
                else        { ST4(9, yo[11],yo[12],yo[13],yo[14]) }
                P1S(16) P1S(17) P1S(18) P1S(19)
                if (h == 0) { ST4(4, yo[16],yo[17],yo[18],yo[19]) }
                else        { ST4(10, yo[15],yo[16],yo[17],yo[18]) }
                P1S(20) P1S(21) P1S(22) P1S(23)
                if (h == 0) { ST4(5, yo[20],yo[21],yo[22],yo[23]) }
                else        { ST4(11, yo[19],yo[20],yo[21],yo[22]) }
                P1S(24)
                if (h == 0) { y2t[Y2I(kk2,6,lane,0)] = yo[24]; }
                else        { ST4(12, yo[23],yo[24],0.0f,0.0f) }
#undef ST4
#undef P1S
#undef P1Q
            } else {
                // pad k: stage zeros so phase 2 needs no guards
                // (z=b3 -> o3=tanh(b3)+0, multiplied by t2=0 -> contributes 0)
                const float4 zv = make_float4(0.f, 0.f, 0.f, 0.f);
                if (h == 0) {
                    *(float4*)&t2s[(kk2*NBATCH + lane)*NAXIS] = zv;
                    for (int q = 0; q < 7; ++q)
                        *(float4*)&y2t[Y2I(kk2,q,lane,0)] = zv;
                } else {
                    for (int q = 7; q < NQ; ++q)
                        *(float4*)&y2t[Y2I(kk2,q,lane,0)] = zv;
                }
            }
        }
        __syncthreads();
        // ================= phase 2: layer 3 + contractions (channel fixed) ========
        {
            const float* w3r[7];
#define W3RI(gi) w3r[gi] = W3 + ((size_t)ch*N3 + gh*N2 + gg[gi])*N2;
            R7(W3RI)
#undef W3RI
            float z0[7], z1[7], z2[7], z3[7];
#define ZIN(gi) z0[gi]=b3v[gi]; z1[gi]=b3v[gi]; z2[gi]=b3v[gi]; z3[gi]=b3v[gi];
            R7(ZIN)
#undef ZIN
#pragma unroll 2
            for (int iq = 0; iq < 12; ++iq) {
                const int io = iq * 4;
                float wa[7], wb[7], wc[7], wd[7];   // wave-uniform -> SGPRs
#define WLD(gi) { wa[gi]=w3r[gi][io+0]; wb[gi]=w3r[gi][io+1]; \
                  wc[gi]=w3r[gi][io+2]; wd[gi]=w3r[gi][io+3]; }
                R7(WLD)
#undef WLD
                const float4 yv0 = *(const float4*)&y2t[Y2I(0, iq, lane, 0)];
                const float4 yv1 = *(const float4*)&y2t[Y2I(1, iq, lane, 0)];
                const float4 yv2 = *(const float4*)&y2t[Y2I(2, iq, lane, 0)];
                const float4 yv3 = *(const float4*)&y2t[Y2I(3, iq, lane, 0)];
#define FK(gi) \
  z0[gi]=fmaf(wd[gi],yv0.w,fmaf(wc[gi],yv0.z,fmaf(wb[gi],yv0.y,fmaf(wa[gi],yv0.x,z0[gi])))); \
  z1[gi]=fmaf(wd[gi],yv1.w,fmaf(wc[gi],yv1.z,fmaf(wb[gi],yv1.y,fmaf(wa[gi],yv1.x,z1[gi])))); \
  z2[gi]=fmaf(wd[gi],yv2.w,fmaf(wc[gi],yv2.z,fmaf(wb[gi],yv2.y,fmaf(wa[gi],yv2.x,z2[gi])))); \
  z3[gi]=fmaf(wd[gi],yv3.w,fmaf(wc[gi],yv3.z,fmaf(wb[gi],yv3.y,fmaf(wa[gi],yv3.x,z3[gi]))));
                R7(FK)
#undef FK
            }
            {   // epilogue i = 48,49 (granule 12; slots 2,3 staged as zero)
                float wa[7], wb[7];
#define WLE(gi) { wa[gi]=w3r[gi][48]; wb[gi]=w3r[gi][49]; }
                R7(WLE)
#undef WLE
                const float4 yv0 = *(const float4*)&y2t[Y2I(0, 12, lane, 0)];
                const float4 yv1 = *(const float4*)&y2t[Y2I(1, 12, lane, 0)];
                const float4 yv2 = *(const float4*)&y2t[Y2I(2, 12, lane, 0)];
                const float4 yv3 = *(const float4*)&y2t[Y2I(3, 12, lane, 0)];
#define FE(gi) \
  z0[gi]=fmaf(wb[gi],yv0.y,fmaf(wa[gi],yv0.x,z0[gi])); \
  z1[gi]=fmaf(wb[gi],yv1.y,fmaf(wa[gi],yv1.x,z1[gi])); \
  z2[gi]=fmaf(wb[gi],yv2.y,fmaf(wa[gi],yv2.x,z2[gi])); \
  z3[gi]=fmaf(wb[gi],yv3.y,fmaf(wa[gi],yv3.x,z3[gi]));
                R7(FE)
#undef FE
            }
            // finish: o3 = tanh(z) + y2[gg]; racc += o3 * t2
            // (residual b32 read is 8-way conflicted -- 28 reads/wave-chunk, accepted)
#define PFG(kq, gi, Z) { \
    const float res = y2t[Y2I(kq, (gg[gi]>>2), lane, (gg[gi]&3))]; \
    const float o3 = tanh_fast(Z[gi]) + res; \
    racc[gi][0]=fmaf(o3,t2v.x,racc[gi][0]); racc[gi][1]=fmaf(o3,t2v.y,racc[gi][1]); \
    racc[gi][2]=fmaf(o3,t2v.z,racc[gi][2]); racc[gi][3]=fmaf(o3,t2v.w,racc[gi][3]); }
#define PFK(kq, Z) { const float4 t2v = *(const float4*)&t2s[((kq)*NBATCH + lane)*NAXIS]; \
    PFG(kq,0,Z) PFG(kq,1,Z) PFG(kq,2,Z) PFG(kq,3,Z) PFG(kq,4,Z) PFG(kq,5,Z) PFG(kq,6,Z) }
            PFK(0, z0) PFK(1, z1) PFK(2, z2) PFK(3, z3)
#undef PFK
#undef PFG
        }
        __syncthreads();
    }

#define PST(gi) if (g0 + (gi) < N2) { \
        float* dp = &out[(lane*NCH + n)*OUTPER + (gh*N2 + g0 + (gi))*NAXIS]; \
        atomicAdd(dp + 0, racc[gi][0]); \
        atomicAdd(dp + 1, racc[gi][1]); \
        atomicAdd(dp + 2, racc[gi][2]); \
        atomicAdd(dp + 3, racc[gi][3]); }
    R7(PST)
#undef PST
#undef Y2I
}

extern "C" void kernel_launch(void* const* d_in, const int* in_sizes, int n_in,
                              void* d_out, int out_size, void* d_ws, size_t ws_size,
                              hipStream_t stream) {
    const float* coords = (const float*)d_in[0];
    const int*   types  = (const int*)d_in[1];
    const float* W1 = (const float*)d_in[2];
    const float* B1 = (const float*)d_in[3];
    const float* W2 = (const float*)d_in[4];
    const float* B2 = (const float*)d_in[5];
    const float* W3 = (const float*)d_in[6];
    const float* B3 = (const float*)d_in[7];
    float* out = (float*)d_out;

    float* t1buf = (float*)d_ws;                          // 128*12*64 floats
    float* ct    = t1buf + NCH * 12 * NBATCH;             // 64*128*3 floats

    hipMemsetAsync(t1buf, 0, (size_t)NCH * 12 * NBATCH * sizeof(float), stream);
    hipMemsetAsync(out, 0, (size_t)out_size * sizeof(float), stream);

    k_transpose<<<(NBATCH*NCH*3 + 255)/256, 256, 0, stream>>>(coords, ct);
    k_mlp <<<NCH*4, 256, 0, stream>>>(ct, types, W1,B1,W2,B2,W3,B3, t1buf);
    k_res2<<<NCH*4, 512, 0, stream>>>(ct, types, W1,B1,W2,B2,W3,B3, t1buf, out);
}

// Round 2
// 964.678 us; speedup vs baseline: 1.0467x; 1.0467x over previous
//
#include <hip/hip_runtime.h>

#define NBATCH 64
#define NCH    128
#define NTYPE  6
#define NK     127
#define N1     25
#define N2     50
#define N3     100
#define NAXIS  4
#define OUTPER 400  // N3*NAXIS
#define W2P    28   // W2 row padded to 28 floats -> every row 16B-aligned (float4 reads)
#define MAXKP  152  // padded sorted-k capacity (127 + 6*3 = 145)
#define MAXC4  38   // max 4-k chunks
#define NQ     13   // i-granules of 4 in phase 2 (50 real + 2 zero-pad = 52)

// ---------- repetition macros: straight-line code, literal indices ONLY ----------
#define R5(M)  M(0) M(1) M(2) M(3) M(4)
#define R7(M)  M(0) M(1) M(2) M(3) M(4) M(5) M(6)
#define R12(M) M(0) M(1) M(2) M(3) M(4) M(5) M(6) M(7) M(8) M(9) M(10) M(11)
#define R25(M) M(0) M(1) M(2) M(3) M(4) M(5) M(6) M(7) M(8) M(9) M(10) M(11) M(12) \
               M(13) M(14) M(15) M(16) M(17) M(18) M(19) M(20) M(21) M(22) M(23) M(24)
#define R25A(M,a) M(a,0) M(a,1) M(a,2) M(a,3) M(a,4) M(a,5) M(a,6) M(a,7) M(a,8) M(a,9) \
               M(a,10) M(a,11) M(a,12) M(a,13) M(a,14) M(a,15) M(a,16) M(a,17) M(a,18) \
               M(a,19) M(a,20) M(a,21) M(a,22) M(a,23) M(a,24)
#define R50(M) R25(M) M(25) M(26) M(27) M(28) M(29) M(30) M(31) M(32) M(33) M(34) \
               M(35) M(36) M(37) M(38) M(39) M(40) M(41) M(42) M(43) M(44) M(45) \
               M(46) M(47) M(48) M(49)

__device__ __forceinline__ float tanh_fast(float x) {
    float e = __expf(2.0f * x);                       // e^{2x}; inf/0 saturate correctly
    return 1.0f - 2.0f * __builtin_amdgcn_rcpf(e + 1.0f);
}

// coords (NB,NC,3) -> ct[(j*3+d)*NB + b]  (lane=b contiguous)
__global__ void k_transpose(const float* __restrict__ coords, float* __restrict__ ct) {
    int t = blockIdx.x * blockDim.x + threadIdx.x;
    if (t >= NBATCH * NCH * 3) return;
    int b  = t & (NBATCH - 1);
    int jd = t >> 6;
    int d  = jd % 3;
    int j  = jd / 3;
    ct[t] = coords[(b * NCH + j) * 3 + d];
}

// plain counting sort (k_mlp)
__device__ __forceinline__ void sort_k_by_type(
    const int* __restrict__ types, int n, int* tysh, int* ks, int* bins, int tid, int nthr)
{
    for (int t = tid; t < NCH; t += nthr) tysh[t] = types[t];
    __syncthreads();
    if (tid == 0) {
        for (int t = 0; t < NTYPE; ++t) bins[t] = 0;
        for (int k = 0; k < NK; ++k) { int j = (k < n) ? k : k + 1; bins[tysh[j]]++; }
        int off = 0;
        for (int t = 0; t < NTYPE; ++t) { int c = bins[t]; bins[t] = off; off += c; }
        for (int k = 0; k < NK; ++k) { int j = (k < n) ? k : k + 1; ks[bins[tysh[j]]++] = k; }
    }
    __syncthreads();
}

// padded counting sort: each 4-k chunk has ONE neighbor type; pads = -1.
// chs[chunk] = neighbor type, aux[0] = number of chunks.
__device__ __forceinline__ void sort_pad(
    const int* __restrict__ types, int n, int* tysh, int* ksp, int* chs, int* aux,
    int tid, int nthr)
{
    for (int t = tid; t < NCH; t += nthr) tysh[t] = types[t];
    __syncthreads();
    if (tid == 0) {
        int cnt[NTYPE], pos[NTYPE];
        for (int t = 0; t < NTYPE; ++t) cnt[t] = 0;
        for (int k = 0; k < NK; ++k) { int j = (k < n) ? k : k + 1; cnt[tysh[j]]++; }
        int c = 0;
        for (int t = 0; t < NTYPE; ++t) {
            pos[t] = c;
            int pc = (cnt[t] + 3) & ~3;
            for (int q = c >> 2; q < (c + pc) >> 2; ++q) chs[q] = t;
            for (int p = c + cnt[t]; p < c + pc; ++p) ksp[p] = -1;
            c += pc;
        }
        aux[0] = c >> 2;
        for (int k = 0; k < NK; ++k) { int j = (k < n) ? k : k + 1; ksp[pos[tysh[j]]++] = k; }
    }
    __syncthreads();
}

// Kernel A: unchanged round-10 structure (sorted k, wave-uniform s_load weights).
__global__ __launch_bounds__(256, 4) void k_mlp(
    const float* __restrict__ ct, const int* __restrict__ types,
    const float* __restrict__ W1, const float* __restrict__ B1,
    const float* __restrict__ W2, const float* __restrict__ B2,
    const float* __restrict__ W3, const float* __restrict__ B3,
    float* __restrict__ t1buf)
{
    __shared__ int ks[NK];
    __shared__ int tysh[NCH];
    __shared__ int bins[NTYPE];

    const int n  = blockIdx.x >> 2;
    const int qc = blockIdx.x & 3;
    const int w  = threadIdx.x >> 6;
    const int b  = threadIdx.x & 63;
    const int k0 = qc * 32 + w * 8;

    sort_k_by_type(types, n, tysh, ks, bins, threadIdx.x, 256);

    const float cx = ct[(n*3+0)*NBATCH + b];
    const float cy = ct[(n*3+1)*NBATCH + b];
    const float cz = ct[(n*3+2)*NBATCH + b];
    const int tn = __builtin_amdgcn_readfirstlane(tysh[n]);

    float t1a[12];
#define TIN(i) t1a[i] = 0.0f;
    R12(TIN)
#undef TIN

    for (int kk = 0; kk < 8; ++kk) {
        const int kidx = k0 + kk;
        if (kidx >= NK) break;
        const int sk = __builtin_amdgcn_readfirstlane(ks[kidx]);
        const int j  = (sk < n) ? sk : sk + 1;
        const int ch = __builtin_amdgcn_readfirstlane(tn * NTYPE + tysh[j]);

        const float dx = cx - ct[(j*3+0)*NBATCH + b];
        const float dy = cy - ct[(j*3+1)*NBATCH + b];
        const float dz = cz - ct[(j*3+2)*NBATCH + b];
        const float d2 = dx*dx + dy*dy + dz*dz;
        const float dd = sqrtf(d2);
        const float dinv = __builtin_amdgcn_rcpf(fmaxf(dd, 1e-12f));
        const float di2 = dinv * dinv;
        const float ax = dx * di2, ay = dy * di2, az = dz * di2;

        const float* w1r = W1 + ch * N1;
        const float* b1r = B1 + ch * N1;
        float y1[N1];
#define L1S(o) y1[o] = tanh_fast(fmaf(dinv, w1r[o], b1r[o]));
        R25(L1S)
#undef L1S

        const float* w2r = W2 + ch * (N2 * N1);
        const float* b2r = B2 + ch * N2;
        const float* w3r = W3 + ch * (N3 * N2);
        float zf[4];
        zf[0] = B3[ch*N3+0]; zf[1] = B3[ch*N3+1];
        zf[2] = B3[ch*N3+2]; zf[3] = B3[ch*N3+3];
        float r[4];
#define MLP2I(o,i) z = fmaf(w2r[(o)*N1+(i)], y1[i], z);
#define MLP2(o) { float z = b2r[o]; R25A(MLP2I,o) \
        float y2o = tanh_fast(z) + y1[(o)%N1]; \
        if ((o) < 4) r[(o)&3] = y2o; \
        zf[0] = fmaf(w3r[0*N2+(o)], y2o, zf[0]); \
        zf[1] = fmaf(w3r[1*N2+(o)], y2o, zf[1]); \
        zf[2] = fmaf(w3r[2*N2+(o)], y2o, zf[2]); \
        zf[3] = fmaf(w3r[3*N2+(o)], y2o, zf[3]); }
        R50(MLP2)
#undef MLP2
#undef MLP2I

#define O4F(f) { float o4 = tanh_fast(zf[f]) + r[f]; \
        t1a[0+(f)] = fmaf(ax, o4, t1a[0+(f)]); \
        t1a[4+(f)] = fmaf(ay, o4, t1a[4+(f)]); \
        t1a[8+(f)] = fmaf(az, o4, t1a[8+(f)]); }
        O4F(0) O4F(1) O4F(2) O4F(3)
#undef O4F
    }

    float* dst = t1buf + (n * 12) * NBATCH + b;   // [n][i][b] lane-coalesced
#define TAT(i) atomicAdd(dst + (i) * NBATCH, t1a[i]);
    R12(TAT)
#undef TAT
}

// Kernel B v3 = v2 structure with the register cap fixed.
// v2 post-mortem: __launch_bounds__(512,4) capped VGPRs at 64 on this toolchain
// (2nd arg behaves as min WORKGROUPS/CU here: 2048-reg pool / (4 wg * 8 waves)
// = 64; the (512,3) cap was ~84, matching the old "~84" observation). Phase 2
// has ~90-100 live VGPRs (racc 28 + z 28 + t1r 12 + yv transients) -> ~30 regs
// spilled to scratch per lane, +0.93 GB HBM traffic/dispatch (FETCH 3.5->512MB,
// WRITE 205->620MB), 684->857us. Fix: (512,2) -> cap 128 under either arg
// interpretation. Occupancy unchanged: LDS 63.5KB caps residency at 2 blocks/CU
// (= 4 waves/SIMD) regardless of VGPR count <= 128.
__global__ __launch_bounds__(512, 2) void k_res2(
    const float* __restrict__ ct, const int* __restrict__ types,
    const float* __restrict__ W1, const float* __restrict__ B1,
    const float* __restrict__ W2, const float* __restrict__ B2,
    const float* __restrict__ W3, const float* __restrict__ B3,
    const float* __restrict__ t1buf, float* __restrict__ out)
{
    __shared__ float y2t[4 * NQ * NBATCH * 4];     // 53248 B  [k][q][b][4]
    __shared__ float t2s[4 * NBATCH * NAXIS];      //  4096 B
    __shared__ float w2s[N2 * W2P];                //  5600 B (rows padded to 28)
    __shared__ float w1s[N1], b1s[N1], b2s[N2];
    __shared__ int   ksp[MAXKP];
    __shared__ int   chs[MAXC4];
    __shared__ int   tysh[NCH];
    __shared__ int   aux[1];

#define Y2I(k,q,b,j) ((((k)*NQ + (q))*NBATCH + (b))*4 + (j))

    const int n    = blockIdx.x >> 2;
    const int gh   = (blockIdx.x >> 1) & 1;
    const int kh   = blockIdx.x & 1;
    const int w    = threadIdx.x >> 6;
    const int lane = threadIdx.x & 63;            // = b in both phases
    const int kk2  = w >> 1;                      // phase-1 k of chunk
    const int h    = w & 1;                       // phase-1 y2 half
    const int tid  = threadIdx.x;

    sort_pad(types, n, tysh, ksp, chs, aux, tid, 512);
    const int nch4 = __builtin_amdgcn_readfirstlane(aux[0]);
    const int c_lo = kh ? (nch4 >> 1) : 0;
    const int c_hi = kh ? nch4 : (nch4 >> 1);

    const int tn = __builtin_amdgcn_readfirstlane(tysh[n]);

    const float cx = ct[(n*3+0)*NBATCH + lane];
    const float cy = ct[(n*3+1)*NBATCH + lane];
    const float cz = ct[(n*3+2)*NBATCH + lane];

    float t1r[12];
#define T1L(i) t1r[i] = t1buf[(n*12 + (i))*NBATCH + lane];
    R12(T1L)
#undef T1L

    const int g0 = __builtin_amdgcn_readfirstlane(w * 7);
    int gg[7];
#define GGI(gi) gg[gi] = ((g0 + (gi)) < N2) ? (g0 + (gi)) : (N2 - 1);
    R7(GGI)
#undef GGI

    float racc[7][4];
#define RIN(gi) racc[gi][0]=0.f; racc[gi][1]=0.f; racc[gi][2]=0.f; racc[gi][3]=0.f;
    R7(RIN)
#undef RIN

    float b3v[7];
    int prevty = -1;

    for (int kc = c_lo; kc < c_hi; ++kc) {
        const int tj = __builtin_amdgcn_readfirstlane(chs[kc]);
        const int ch = tn * NTYPE + tj;
        if (tj != prevty) {                        // block-uniform branch
            // stage channel weights to LDS (prev P2 done: trailing barrier)
            for (int idx = tid; idx < N2*N1; idx += 512)
                w2s[(idx / N1) * W2P + (idx % N1)] = W2[ch*(N2*N1) + idx];
            if (tid < N1) { w1s[tid] = W1[ch*N1+tid]; b1s[tid] = B1[ch*N1+tid]; }
            if (tid < N2) b2s[tid] = B2[ch*N2+tid];
#define B3L(gi) b3v[gi] = B3[ch*N3 + gh*N2 + gg[gi]];
            R7(B3L)
#undef B3L
            prevty = tj;
            __syncthreads();
        }
        const int kb = kc * 4;
        // ================= phase 1: stage y2 (+t2) for 4 k's (one channel) ========
        {
            const int sk = __builtin_amdgcn_readfirstlane(ksp[kb + kk2]);
            if (sk >= 0) {
                const int j = (sk < n) ? sk : sk + 1;
                const float dx = cx - ct[(j*3+0)*NBATCH + lane];
                const float dy = cy - ct[(j*3+1)*NBATCH + lane];
                const float dz = cz - ct[(j*3+2)*NBATCH + lane];
                const float d2 = dx*dx + dy*dy + dz*dz;
                const float dd = sqrtf(d2);
                const float dinv = __builtin_amdgcn_rcpf(fmaxf(dd, 1e-12f));

                if (h == 0) {
                    const float di2 = dinv * dinv;
                    const float ax = dx * di2, ay = dy * di2, az = dz * di2;
                    float4 t2v;
                    t2v.x = ax*t1r[0] + ay*t1r[4] + az*t1r[8];
                    t2v.y = ax*t1r[1] + ay*t1r[5] + az*t1r[9];
                    t2v.z = ax*t1r[2] + ay*t1r[6] + az*t1r[10];
                    t2v.w = ax*t1r[3] + ay*t1r[7] + az*t1r[11];
                    *(float4*)&t2s[(kk2*NBATCH + lane)*NAXIS] = t2v;
                }

                float y1[N1];
#define L1S(o) y1[o] = tanh_fast(fmaf(dinv, w1s[o], b1s[o]));
                R25(L1S)
#undef L1S
                const int ob = h * N1;            // 0 or 25
                // yo[oi] = y2[ob+oi]; residual y1[(ob+oi)%25] = y1[oi] for both h.
                float yo[N1];
#define P1Q(oi,q) { float4 wq = *(const float4*)&w2s[(ob+(oi))*W2P + (q)*4]; \
                    z = fmaf(wq.x, y1[(q)*4+0], z); z = fmaf(wq.y, y1[(q)*4+1], z); \
                    z = fmaf(wq.z, y1[(q)*4+2], z); z = fmaf(wq.w, y1[(q)*4+3], z); }
#define P1S(oi) { float z = b2s[ob+(oi)]; \
                  P1Q(oi,0) P1Q(oi,1) P1Q(oi,2) P1Q(oi,3) P1Q(oi,4) P1Q(oi,5) \
                  z = fmaf(w2s[(ob+(oi))*W2P + 24], y1[24], z); \
                  yo[oi] = tanh_fast(z) + y1[oi]; }
#define ST4(q,a0,a1,a2,a3) { float4 v; v.x=(a0); v.y=(a1); v.z=(a2); v.w=(a3); \
                  *(float4*)&y2t[Y2I(kk2,(q),lane,0)] = v; }
                // interleave compute/store per 4 outputs to keep yo lifetimes short.
                // h=0 covers o 0..24 (granules 0..5 + g6 slot0);
                // h=1 covers o 25..49 (g6 slots 1..3, granules 7..11, g12={48,49,0,0}).
                P1S(0) P1S(1) P1S(2) P1S(3)
                if (h == 0) { ST4(0, yo[0],yo[1],yo[2],yo[3]) }
                else { y2t[Y2I(kk2,6,lane,1)] = yo[0];
                       y2t[Y2I(kk2,6,lane,2)] = yo[1];
                       y2t[Y2I(kk2,6,lane,3)] = yo[2]; }
                P1S(4) P1S(5) P1S(6) P1S(7)
                if (h == 0) { ST4(1, yo[4],yo[5],yo[6],yo[7]) }
                else        { ST4(7, yo[3],yo[4],yo[5],yo[6]) }
                P1S(8) P1S(9) P1S(10) P1S(11)
                if (h == 0) { ST4(2, yo[8],yo[9],yo[10],yo[11]) }
                else        { ST4(8, yo[7],yo[8],yo[9],yo[10]) }
                P1S(12) P1S(13) P1S(14) P1S(15)
                if (h == 0) { ST4(3, yo[12],yo[13],yo[14],yo[15]) }
                else        { ST4(9, yo[11],yo[12],yo[13],yo[14]) }
                P1S(16) P1S(17) P1S(18) P1S(19)
                if (h == 0) { ST4(4, yo[16],yo[17],yo[18],yo[19]) }
                else        { ST4(10, yo[15],yo[16],yo[17],yo[18]) }
                P1S(20) P1S(21) P1S(22) P1S(23)
                if (h == 0) { ST4(5, yo[20],yo[21],yo[22],yo[23]) }
                else        { ST4(11, yo[19],yo[20],yo[21],yo[22]) }
                P1S(24)
                if (h == 0) { y2t[Y2I(kk2,6,lane,0)] = yo[24]; }
                else        { ST4(12, yo[23],yo[24],0.0f,0.0f) }
#undef ST4
#undef P1S
#undef P1Q
            } else {
                // pad k: stage zeros so phase 2 needs no guards
                // (z=b3 -> o3=tanh(b3)+0, multiplied by t2=0 -> contributes 0)
                const float4 zv = make_float4(0.f, 0.f, 0.f, 0.f);
                if (h == 0) {
                    *(float4*)&t2s[(kk2*NBATCH + lane)*NAXIS] = zv;
                    for (int q = 0; q < 7; ++q)
                        *(float4*)&y2t[Y2I(kk2,q,lane,0)] = zv;
                } else {
                    for (int q = 7; q < NQ; ++q)
                        *(float4*)&y2t[Y2I(kk2,q,lane,0)] = zv;
                }
            }
        }
        __syncthreads();
        // ================= phase 2: layer 3 + contractions (channel fixed) ========
        {
            const float* w3r[7];
#define W3RI(gi) w3r[gi] = W3 + ((size_t)ch*N3 + gh*N2 + gg[gi])*N2;
            R7(W3RI)
#undef W3RI
            float z0[7], z1[7], z2[7], z3[7];
#define ZIN(gi) z0[gi]=b3v[gi]; z1[gi]=b3v[gi]; z2[gi]=b3v[gi]; z3[gi]=b3v[gi];
            R7(ZIN)
#undef ZIN
#pragma unroll 2
            for (int iq = 0; iq < 12; ++iq) {
                const int io = iq * 4;
                float wa[7], wb[7], wc[7], wd[7];   // wave-uniform -> SGPRs
#define WLD(gi) { wa[gi]=w3r[gi][io+0]; wb[gi]=w3r[gi][io+1]; \
                  wc[gi]=w3r[gi][io+2]; wd[gi]=w3r[gi][io+3]; }
                R7(WLD)
#undef WLD
                const float4 yv0 = *(const float4*)&y2t[Y2I(0, iq, lane, 0)];
                const float4 yv1 = *(const float4*)&y2t[Y2I(1, iq, lane, 0)];
                const float4 yv2 = *(const float4*)&y2t[Y2I(2, iq, lane, 0)];
                const float4 yv3 = *(const float4*)&y2t[Y2I(3, iq, lane, 0)];
#define FK(gi) \
  z0[gi]=fmaf(wd[gi],yv0.w,fmaf(wc[gi],yv0.z,fmaf(wb[gi],yv0.y,fmaf(wa[gi],yv0.x,z0[gi])))); \
  z1[gi]=fmaf(wd[gi],yv1.w,fmaf(wc[gi],yv1.z,fmaf(wb[gi],yv1.y,fmaf(wa[gi],yv1.x,z1[gi])))); \
  z2[gi]=fmaf(wd[gi],yv2.w,fmaf(wc[gi],yv2.z,fmaf(wb[gi],yv2.y,fmaf(wa[gi],yv2.x,z2[gi])))); \
  z3[gi]=fmaf(wd[gi],yv3.w,fmaf(wc[gi],yv3.z,fmaf(wb[gi],yv3.y,fmaf(wa[gi],yv3.x,z3[gi]))));
                R7(FK)
#undef FK
            }
            {   // epilogue i = 48,49 (granule 12; slots 2,3 staged as zero)
                float wa[7], wb[7];
#define WLE(gi) { wa[gi]=w3r[gi][48]; wb[gi]=w3r[gi][49]; }
                R7(WLE)
#undef WLE
                const float4 yv0 = *(const float4*)&y2t[Y2I(0, 12, lane, 0)];
                const float4 yv1 = *(const float4*)&y2t[Y2I(1, 12, lane, 0)];
                const float4 yv2 = *(const float4*)&y2t[Y2I(2, 12, lane, 0)];
                const float4 yv3 = *(const float4*)&y2t[Y2I(3, 12, lane, 0)];
#define FE(gi) \
  z0[gi]=fmaf(wb[gi],yv0.y,fmaf(wa[gi],yv0.x,z0[gi])); \
  z1[gi]=fmaf(wb[gi],yv1.y,fmaf(wa[gi],yv1.x,z1[gi])); \
  z2[gi]=fmaf(wb[gi],yv2.y,fmaf(wa[gi],yv2.x,z2[gi])); \
  z3[gi]=fmaf(wb[gi],yv3.y,fmaf(wa[gi],yv3.x,z3[gi]));
                R7(FE)
#undef FE
            }
            // finish: o3 = tanh(z) + y2[gg]; racc += o3 * t2
            // (residual b32 read is 8-way conflicted -- 28 reads/wave-chunk,
            //  ~2.5% of kernel cycles at 13.5M conflict-cycles -- accepted)
#define PFG(kq, gi, Z) { \
    const float res = y2t[Y2I(kq, (gg[gi]>>2), lane, (gg[gi]&3))]; \
    const float o3 = tanh_fast(Z[gi]) + res; \
    racc[gi][0]=fmaf(o3,t2v.x,racc[gi][0]); racc[gi][1]=fmaf(o3,t2v.y,racc[gi][1]); \
    racc[gi][2]=fmaf(o3,t2v.z,racc[gi][2]); racc[gi][3]=fmaf(o3,t2v.w,racc[gi][3]); }
#define PFK(kq, Z) { const float4 t2v = *(const float4*)&t2s[((kq)*NBATCH + lane)*NAXIS]; \
    PFG(kq,0,Z) PFG(kq,1,Z) PFG(kq,2,Z) PFG(kq,3,Z) PFG(kq,4,Z) PFG(kq,5,Z) PFG(kq,6,Z) }
            PFK(0, z0) PFK(1, z1) PFK(2, z2) PFK(3, z3)
#undef PFK
#undef PFG
        }
        __syncthreads();
    }

#define PST(gi) if (g0 + (gi) < N2) { \
        float* dp = &out[(lane*NCH + n)*OUTPER + (gh*N2 + g0 + (gi))*NAXIS]; \
        atomicAdd(dp + 0, racc[gi][0]); \
        atomicAdd(dp + 1, racc[gi][1]); \
        atomicAdd(dp + 2, racc[gi][2]); \
        atomicAdd(dp + 3, racc[gi][3]); }
    R7(PST)
#undef PST
#undef Y2I
}

extern "C" void kernel_launch(void* const* d_in, const int* in_sizes, int n_in,
                              void* d_out, int out_size, void* d_ws, size_t ws_size,
                              hipStream_t stream) {
    const float* coords = (const float*)d_in[0];
    const int*   types  = (const int*)d_in[1];
    const float* W1 = (const float*)d_in[2];
    const float* B1 = (const float*)d_in[3];
    const float* W2 = (const float*)d_in[4];
    const float* B2 = (const float*)d_in[5];
    const float* W3 = (const float*)d_in[6];
    const float* B3 = (const float*)d_in[7];
    float* out = (float*)d_out;

    float* t1buf = (float*)d_ws;                          // 128*12*64 floats
    float* ct    = t1buf + NCH * 12 * NBATCH;             // 64*128*3 floats

    hipMemsetAsync(t1buf, 0, (size_t)NCH * 12 * NBATCH * sizeof(float), stream);
    hipMemsetAsync(out, 0, (size_t)out_size * sizeof(float), stream);

    k_transpose<<<(NBATCH*NCH*3 + 255)/256, 256, 0, stream>>>(coords, ct);
    k_mlp <<<NCH*4, 256, 0, stream>>>(ct, types, W1,B1,W2,B2,W3,B3, t1buf);
    k_res2<<<NCH*4, 512, 0, stream>>>(ct, types, W1,B1,W2,B2,W3,B3, t1buf, out);
}